// Round 5
// baseline (10128.716 us; speedup 1.0000x reference)
//
#include <hip/hip_runtime.h>
#include <cstdint>
#include <cstddef>

#define D_MODEL 512
#define N_HEADS 8
#define HEAD_E  64
#define SEQ_L   2048
#define BATCH   2
#define KSEL    38            // int(5*log(2048)) = 38
#define M_ROWS  (BATCH*SEQ_L) // 4096

// ---------------------------------------------------------------------------
// f32 GEMM: C = A @ W.T + b. Tile 64x64, BK=32, 256 thr, 4x4 micro.
// ---------------------------------------------------------------------------
__global__ __launch_bounds__(256) void gemm_bias_kernel(
    const float* __restrict__ A, const float* __restrict__ W,
    const float* __restrict__ bias, float* __restrict__ C,
    int M, int N, int K)
{
  __shared__ float As[64][36];
  __shared__ float Ws[64][36];
  const int t  = threadIdx.x;
  const int tx = t & 15, ty = t >> 4;
  const int bm = blockIdx.y << 6, bn = blockIdx.x << 6;

  float acc[4][4] = {};

  for (int k0 = 0; k0 < K; k0 += 32) {
    __syncthreads();
#pragma unroll
    for (int i = 0; i < 2; ++i) {
      int f = t + (i << 8);
      int r = f >> 3, c = (f & 7) << 2;
      *(float4*)&As[r][c] = *(const float4*)&A[(size_t)(bm + r) * K + k0 + c];
      *(float4*)&Ws[r][c] = *(const float4*)&W[(size_t)(bn + r) * K + k0 + c];
    }
    __syncthreads();
#pragma unroll
    for (int kk = 0; kk < 32; kk += 4) {
      float4 av[4], wv[4];
#pragma unroll
      for (int i = 0; i < 4; ++i) av[i] = *(const float4*)&As[ty * 4 + i][kk];
#pragma unroll
      for (int j = 0; j < 4; ++j) wv[j] = *(const float4*)&Ws[tx + 16 * j][kk];
#pragma unroll
      for (int i = 0; i < 4; ++i)
#pragma unroll
        for (int j = 0; j < 4; ++j)
          acc[i][j] += av[i].x * wv[j].x + av[i].y * wv[j].y +
                       av[i].z * wv[j].z + av[i].w * wv[j].w;
    }
  }

#pragma unroll
  for (int i = 0; i < 4; ++i) {
    int row = bm + ty * 4 + i;
#pragma unroll
    for (int j = 0; j < 4; ++j) {
      int col = bn + tx + 16 * j;
      C[(size_t)row * N + col] = acc[i][j] + bias[col];
    }
  }
}

// ---------------------------------------------------------------------------
// Dual f64-accumulate GEMM (z=0: Q, z=1: K + f32 copy). f32 inputs, exact
// products, f64 accumulation.
// ---------------------------------------------------------------------------
__global__ __launch_bounds__(256) void gemm_bias_f64_dual_kernel(
    const float* __restrict__ A,
    const float* __restrict__ Wq, const float* __restrict__ bq, double* __restrict__ Qd,
    const float* __restrict__ Wk, const float* __restrict__ bk, double* __restrict__ Kd,
    float* __restrict__ Kf, int M, int N, int K)
{
  const float* W   = (blockIdx.z == 0) ? Wq : Wk;
  const float* bias= (blockIdx.z == 0) ? bq : bk;
  double*      Cd  = (blockIdx.z == 0) ? Qd : Kd;
  float*       Cf  = (blockIdx.z == 0) ? nullptr : Kf;

  __shared__ float As[64][36];
  __shared__ float Ws[64][36];
  const int t  = threadIdx.x;
  const int tx = t & 15, ty = t >> 4;
  const int bm = blockIdx.y << 6, bn = blockIdx.x << 6;

  double acc[4][4] = {};

  for (int k0 = 0; k0 < K; k0 += 32) {
    __syncthreads();
#pragma unroll
    for (int i = 0; i < 2; ++i) {
      int f = t + (i << 8);
      int r = f >> 3, c = (f & 7) << 2;
      *(float4*)&As[r][c] = *(const float4*)&A[(size_t)(bm + r) * K + k0 + c];
      *(float4*)&Ws[r][c] = *(const float4*)&W[(size_t)(bn + r) * K + k0 + c];
    }
    __syncthreads();
#pragma unroll
    for (int kk = 0; kk < 32; kk += 4) {
      float4 av[4], wv[4];
#pragma unroll
      for (int i = 0; i < 4; ++i) av[i] = *(const float4*)&As[ty * 4 + i][kk];
#pragma unroll
      for (int j = 0; j < 4; ++j) wv[j] = *(const float4*)&Ws[tx + 16 * j][kk];
#pragma unroll
      for (int i = 0; i < 4; ++i)
#pragma unroll
        for (int j = 0; j < 4; ++j)
          acc[i][j] += (double)av[i].x * (double)wv[j].x
                     + (double)av[i].y * (double)wv[j].y
                     + (double)av[i].z * (double)wv[j].z
                     + (double)av[i].w * (double)wv[j].w;
    }
  }

#pragma unroll
  for (int i = 0; i < 4; ++i) {
    int row = bm + ty * 4 + i;
#pragma unroll
    for (int j = 0; j < 4; ++j) {
      int col = bn + tx + 16 * j;
      double v = acc[i][j] + (double)bias[col];
      Cd[(size_t)row * N + col] = v;
      if (Cf) Cf[(size_t)row * N + col] = (float)v;
    }
  }
}

// ---------------------------------------------------------------------------
// Fused ProbSparse attention v4 — 2 queries/wave, double-buffered K tiles
// with async-split staging (issue-early / write-late).
// grid (L/8, B*H), block 256 = 4 waves; wave w owns queries 2w, 2w+1.
// Score phase: 32 K-tiles (64 keys) in XOR-swizzled LDS dbuf; Q via
// wave-uniform LDS broadcast; scores -> va[32]/vb[32] regs (full unroll).
// Selection per query: bisect threshold (40<=count<=64) -> ballot-compact
// -> 64-wide bitonic sort -> fast f32 softmax if rank37/38 gap > 1e-4,
// else exact f64 rescore of candidates. PV via shfl broadcast.
// ---------------------------------------------------------------------------
__global__ __launch_bounds__(256) void attn_kernel(
    const double* __restrict__ Qd, const float* __restrict__ Kf,
    const double* __restrict__ Kd, const float* __restrict__ Vm,
    float* __restrict__ AO)
{
  __shared__ float  Ks[2][64 * 64];  // swizzled float4 K tiles, 2 x 16 KB
  __shared__ float  Qs[8][64];       // f32 Q rows (broadcast reads)
  __shared__ double Qsd[8][64];      // f64 Q rows for rescore
  __shared__ float  cvs[4][64];      // per-wave compacted candidate values
  __shared__ int    cis[4][64];      // per-wave compacted candidate indices

  const int t  = threadIdx.x;
  const int w  = t >> 6;    // wave id
  const int l  = t & 63;    // lane
  const int bh = blockIdx.y;
  const int b  = bh >> 3, h = bh & 7;
  const int q0 = blockIdx.x << 3;    // 8 queries per block
  const size_t rowbase = (size_t)b * SEQ_L;
  const float* Kb = Kf + rowbase * D_MODEL + h * HEAD_E;
  const float* Vb = Vm + rowbase * D_MODEL + h * HEAD_E;

  // stage 8 Q rows (f64 + f32 cast): thread t -> flat pair (query t>>5, dims)
  {
    int qq = t >> 5, dd = (t & 31) << 1;
    double2 qv = *(const double2*)&Qd[(rowbase + q0 + qq) * D_MODEL + h * HEAD_E + dd];
    Qsd[qq][dd]     = qv.x;  Qsd[qq][dd + 1] = qv.y;
    Qs[qq][dd]      = (float)qv.x;  Qs[qq][dd + 1]  = (float)qv.y;
  }

  const int qa = 2 * w, qb = 2 * w + 1;

  // prologue: stage tile 0 into buf 0
  float4 pre[4];
#pragma unroll
  for (int i = 0; i < 4; ++i) {
    int f = t + (i << 8);
    int r = f >> 4, c4 = f & 15;
    pre[i] = *(const float4*)&Kb[(size_t)r * D_MODEL + (c4 << 2)];
  }
#pragma unroll
  for (int i = 0; i < 4; ++i) {
    int f = t + (i << 8);
    int r = f >> 4, c4 = f & 15;
    ((float4*)Ks[0])[(r << 4) | (c4 ^ (r & 15))] = pre[i];
  }
  __syncthreads();

  float va[32], vb[32];      // scores for the wave's two queries
#pragma unroll
  for (int ti = 0; ti < 32; ++ti) {
    const int buf = ti & 1;
    // issue next-tile global loads early (latency hides under compute)
    if (ti < 31) {
#pragma unroll
      for (int i = 0; i < 4; ++i) {
        int f = t + (i << 8);
        int r = f >> 4, c4 = f & 15;
        pre[i] = *(const float4*)&Kb[(size_t)(((ti + 1) << 6) + r) * D_MODEL + (c4 << 2)];
      }
    }
    // compute on current buffer
    float a0 = 0.f, a1 = 0.f, b0 = 0.f, b1 = 0.f;
#pragma unroll
    for (int e4 = 0; e4 < 16; ++e4) {
      float4 kv  = ((const float4*)Ks[buf])[(l << 4) | (e4 ^ (l & 15))];
      float4 qva = *(const float4*)&Qs[qa][e4 << 2];   // wave-uniform broadcast
      float4 qvb = *(const float4*)&Qs[qb][e4 << 2];
      if (e4 & 1) {
        a1 += qva.x * kv.x + qva.y * kv.y + qva.z * kv.z + qva.w * kv.w;
        b1 += qvb.x * kv.x + qvb.y * kv.y + qvb.z * kv.z + qvb.w * kv.w;
      } else {
        a0 += qva.x * kv.x + qva.y * kv.y + qva.z * kv.z + qva.w * kv.w;
        b0 += qvb.x * kv.x + qvb.y * kv.y + qvb.z * kv.z + qvb.w * kv.w;
      }
    }
    va[ti] = (a0 + a1) * 0.125f;   // 1/sqrt(64)
    vb[ti] = (b0 + b1) * 0.125f;
    __syncthreads();               // all waves done reading buf^1's old data
    if (ti < 31) {
#pragma unroll
      for (int i = 0; i < 4; ++i) {
        int f = t + (i << 8);
        int r = f >> 4, c4 = f & 15;
        ((float4*)Ks[buf ^ 1])[(r << 4) | (c4 ^ (r & 15))] = pre[i];
      }
      __syncthreads();             // buf^1 ready for next iteration
    }
  }

  // ---- per-query selection + softmax + PV ----
  auto process_query = [&](const float (&v)[32], int qidx) {
    // wave max
    float m = v[0];
#pragma unroll
    for (int j = 1; j < 32; ++j) m = fmaxf(m, v[j]);
#pragma unroll
    for (int off = 1; off < 64; off <<= 1) m = fmaxf(m, __shfl_xor(m, off));

    auto countge = [&](float T) -> int {
      int c = 0;
#pragma unroll
      for (int j = 0; j < 32; ++j) c += (v[j] >= T) ? 1 : 0;
#pragma unroll
      for (int off = 1; off < 64; off <<= 1) c += __shfl_xor(c, off);
      return c;  // wave-uniform
    };

    // bisect threshold: invariant count(>=lo) >= 40; shrink until <= 64
    float lo = m - 0.5f;
    int C = countge(lo);
    float step = 1.0f;
    while (C < 40) {
      lo -= step; step *= 2.0f;
      if (step > 1.0e30f) { lo = -3.0e38f; C = 2048; break; }
      C = countge(lo);
    }
    float hi = m;
    for (int it = 0; it < 24 && C > 64; ++it) {
      float mid = 0.5f * (lo + hi);
      int cm = countge(mid);
      if (cm >= 40) { lo = mid; C = cm; } else hi = mid;
    }
    const int C2 = (C < 64) ? C : 64;

    // ballot-compact candidates (>= lo) in index order
    int base = 0;
#pragma unroll
    for (int j = 0; j < 32; ++j) {
      bool in = (v[j] >= lo);
      unsigned long long mk = __ballot(in);
      if (in) {
        int pos = base + (int)__popcll(mk & ((1ull << l) - 1ull));
        if (pos < 64) { cvs[w][pos] = v[j]; cis[w][pos] = (j << 6) | l; }
      }
      base += (int)__popcll(mk);
    }
    __syncthreads();   // aligned across waves (each calls twice)

    float cval = (l < C2) ? cvs[w][l] : -3.0e38f;
    int   cidx = (l < C2) ? cis[w][l] : (SEQ_L + l);

    // bitonic sort 64 lanes: value desc, index asc on ties
#pragma unroll
    for (int sz = 2; sz <= 64; sz <<= 1) {
#pragma unroll
      for (int st = sz >> 1; st >= 1; st >>= 1) {
        float ov = __shfl_xor(cval, st);
        int   oi = __shfl_xor(cidx, st);
        bool ob    = (ov > cval) || ((ov == cval) && (oi < cidx));
        bool dir   = ((l & sz) == 0);
        bool lower = ((l & st) == 0);
        bool take  = (ob == (lower == dir));
        if (take) { cval = ov; cidx = oi; }
      }
    }

    // weights
    float v37 = __shfl(cval, 37);
    float v38 = __shfl(cval, 38);
    const bool tight = (v37 - v38 < 1e-4f) || (C > 64);
    float myw;
    if (!tight) {
      myw = (l < KSEL) ? __expf(cval - m) : 0.f;
    } else {
      // rare: f64 rescore of all candidates, exact f64 top-38
      double d = -1.0e300;
      if (l < C2) {
        const double* kr = Kd + (rowbase + cidx) * D_MODEL + h * HEAD_E;
        double acc = 0.0;
#pragma unroll 8
        for (int e = 0; e < 64; ++e) acc += Qsd[qidx][e] * kr[e];
        d = acc * 0.125;
      }
      int myi = (l < C2) ? cidx : (SEQ_L + l);
      double mxd = -1.0e300; int rank = 0;
      for (int j = 0; j < 64; ++j) {
        double dj = __shfl(d, j);
        int    ij = __shfl(myi, j);
        if (dj > mxd) mxd = dj;
        rank += (dj > d) || ((dj == d) && (ij < myi));
      }
      myw = (l < C2 && rank < KSEL) ? __expf((float)(d - mxd)) : 0.f;
    }

    float psum = myw;
#pragma unroll
    for (int off = 1; off < 64; off <<= 1) psum += __shfl_xor(psum, off);
    const float inv = 1.0f / psum;

    // PV: lane = head dim; broadcast (weight, idx) from candidate lanes
    float acc = 0.f;
    const int nn = tight ? 64 : KSEL;
    for (int j = 0; j < nn; ++j) {
      float wj = __shfl(myw, j);        // wave-uniform
      if (wj != 0.f) {
        int sj = __shfl(cidx, j);
        acc += wj * Vb[(size_t)sj * D_MODEL + l];
      }
    }
    AO[(rowbase + q0 + qidx) * D_MODEL + h * HEAD_E + l] = acc * inv;
  };

  process_query(va, qa);
  process_query(vb, qb);
}

// ---------------------------------------------------------------------------
extern "C" void kernel_launch(void* const* d_in, const int* in_sizes, int n_in,
                              void* d_out, int out_size, void* d_ws, size_t ws_size,
                              hipStream_t stream) {
  const float* x  = (const float*)d_in[0];
  const float* Wq = (const float*)d_in[1];
  const float* bq = (const float*)d_in[2];
  const float* Wk = (const float*)d_in[3];
  const float* bk = (const float*)d_in[4];
  const float* Wv = (const float*)d_in[5];
  const float* bv = (const float*)d_in[6];
  const float* Wo = (const float*)d_in[7];
  const float* bo = (const float*)d_in[8];
  float* out = (float*)d_out;

  char* ws = (char*)d_ws;
  const size_t MAT = (size_t)M_ROWS * D_MODEL;  // 2M elements
  double* Qd = (double*)ws;                     // 16 MB
  double* Kd = (double*)(ws + MAT * 8);         // 16 MB
  float*  Kf = (float*)(ws + MAT * 16);         // 8 MB
  float*  Vf = (float*)(ws + MAT * 20);         // 8 MB
  float*  AO = (float*)(ws + MAT * 24);         // 8 MB

  dim3 ggrid(D_MODEL / 64, M_ROWS / 64);        // (8, 64)
  dim3 dgrid(D_MODEL / 64, M_ROWS / 64, 2);     // (8, 64, 2)
  gemm_bias_f64_dual_kernel<<<dgrid, 256, 0, stream>>>(
      x, Wq, bq, Qd, Wk, bk, Kd, Kf, M_ROWS, D_MODEL, D_MODEL);
  gemm_bias_kernel<<<ggrid, 256, 0, stream>>>(x, Wv, bv, Vf, M_ROWS, D_MODEL, D_MODEL);

  attn_kernel<<<dim3(SEQ_L / 8, BATCH * N_HEADS), 256, 0, stream>>>(Qd, Kf, Kd, Vf, AO);

  gemm_bias_kernel<<<ggrid, 256, 0, stream>>>(AO, Wo, bo, out, M_ROWS, D_MODEL, D_MODEL);
}

// Round 8
// 1311.019 us; speedup vs baseline: 7.7258x; 7.7258x over previous
//
#include <hip/hip_runtime.h>
#include <hip/hip_fp16.h>
#include <cstdint>
#include <cstddef>

#define D_MODEL 512
#define N_HEADS 8
#define HEAD_E  64
#define SEQ_L   2048
#define BATCH   2
#define KSEL    38            // int(5*log(2048)) = 38
#define M_ROWS  (BATCH*SEQ_L) // 4096
#define SP      2050          // S row stride (f16): odd dword stride de-banks rows
#define CCAP    192           // candidate cap (3 per lane); overflow -> exact rescan

typedef short bf16x8 __attribute__((ext_vector_type(8)));
typedef float f32x4  __attribute__((ext_vector_type(4)));

static __device__ __forceinline__ unsigned short f2bf(float x) {
  uint32_t u = __float_as_uint(x);
  return (unsigned short)((u + 0x7FFF + ((u >> 16) & 1)) >> 16);  // RNE
}

// ---------------------------------------------------------------------------
// Fused QKV f32 GEMM: z=0:Q, z=1:K, z=2:V. C = x @ W.T + b.
// Q,K also emit bf16 copies for the MFMA score scan.
// ---------------------------------------------------------------------------
__global__ __launch_bounds__(256) void gemm_qkv_kernel(
    const float* __restrict__ A,
    const float* __restrict__ Wq, const float* __restrict__ bq,
    const float* __restrict__ Wk, const float* __restrict__ bk,
    const float* __restrict__ Wv, const float* __restrict__ bv,
    float* __restrict__ Qf, float* __restrict__ Kf, float* __restrict__ Vf,
    unsigned short* __restrict__ Qh, unsigned short* __restrict__ Kh)
{
  const int z = blockIdx.z;
  const float* W    = (z == 0) ? Wq : ((z == 1) ? Wk : Wv);
  const float* bias = (z == 0) ? bq : ((z == 1) ? bk : bv);
  float* C          = (z == 0) ? Qf : ((z == 1) ? Kf : Vf);
  unsigned short* Ch = (z == 0) ? Qh : ((z == 1) ? Kh : nullptr);

  __shared__ float As[64][36];
  __shared__ float Ws[64][36];
  const int t  = threadIdx.x;
  const int tx = t & 15, ty = t >> 4;
  const int bm = blockIdx.y << 6, bn = blockIdx.x << 6;

  float acc[4][4] = {};

  for (int k0 = 0; k0 < D_MODEL; k0 += 32) {
    __syncthreads();
#pragma unroll
    for (int i = 0; i < 2; ++i) {
      int f = t + (i << 8);
      int r = f >> 3, c = (f & 7) << 2;
      *(float4*)&As[r][c] = *(const float4*)&A[(size_t)(bm + r) * D_MODEL + k0 + c];
      *(float4*)&Ws[r][c] = *(const float4*)&W[(size_t)(bn + r) * D_MODEL + k0 + c];
    }
    __syncthreads();
#pragma unroll
    for (int kk = 0; kk < 32; kk += 4) {
      float4 av[4], wv[4];
#pragma unroll
      for (int i = 0; i < 4; ++i) av[i] = *(const float4*)&As[ty * 4 + i][kk];
#pragma unroll
      for (int j = 0; j < 4; ++j) wv[j] = *(const float4*)&Ws[tx + 16 * j][kk];
#pragma unroll
      for (int i = 0; i < 4; ++i)
#pragma unroll
        for (int j = 0; j < 4; ++j)
          acc[i][j] += av[i].x * wv[j].x + av[i].y * wv[j].y +
                       av[i].z * wv[j].z + av[i].w * wv[j].w;
    }
  }

#pragma unroll
  for (int i = 0; i < 4; ++i) {
    int row = bm + ty * 4 + i;
#pragma unroll
    for (int j = 0; j < 4; ++j) {
      int col = bn + tx + 16 * j;
      float v = acc[i][j] + bias[col];
      size_t idx = (size_t)row * D_MODEL + col;
      C[idx] = v;
      if (Ch) Ch[idx] = f2bf(v);
    }
  }
}

// ---------------------------------------------------------------------------
// f32 GEMM (output projection): C = A @ W.T + b
// ---------------------------------------------------------------------------
__global__ __launch_bounds__(256) void gemm_bias_kernel(
    const float* __restrict__ A, const float* __restrict__ W,
    const float* __restrict__ bias, float* __restrict__ C,
    int M, int N, int K)
{
  __shared__ float As[64][36];
  __shared__ float Ws[64][36];
  const int t  = threadIdx.x;
  const int tx = t & 15, ty = t >> 4;
  const int bm = blockIdx.y << 6, bn = blockIdx.x << 6;

  float acc[4][4] = {};

  for (int k0 = 0; k0 < K; k0 += 32) {
    __syncthreads();
#pragma unroll
    for (int i = 0; i < 2; ++i) {
      int f = t + (i << 8);
      int r = f >> 3, c = (f & 7) << 2;
      *(float4*)&As[r][c] = *(const float4*)&A[(size_t)(bm + r) * K + k0 + c];
      *(float4*)&Ws[r][c] = *(const float4*)&W[(size_t)(bn + r) * K + k0 + c];
    }
    __syncthreads();
#pragma unroll
    for (int kk = 0; kk < 32; kk += 4) {
      float4 av[4], wv[4];
#pragma unroll
      for (int i = 0; i < 4; ++i) av[i] = *(const float4*)&As[ty * 4 + i][kk];
#pragma unroll
      for (int j = 0; j < 4; ++j) wv[j] = *(const float4*)&Ws[tx + 16 * j][kk];
#pragma unroll
      for (int i = 0; i < 4; ++i)
#pragma unroll
        for (int j = 0; j < 4; ++j)
          acc[i][j] += av[i].x * wv[j].x + av[i].y * wv[j].y +
                       av[i].z * wv[j].z + av[i].w * wv[j].w;
    }
  }

#pragma unroll
  for (int i = 0; i < 4; ++i) {
    int row = bm + ty * 4 + i;
#pragma unroll
    for (int j = 0; j < 4; ++j) {
      int col = bn + tx + 16 * j;
      C[(size_t)row * N + col] = acc[i][j] + bias[col];
    }
  }
}

// ---------------------------------------------------------------------------
// Per-(b,h,e) max |K_e| over keys — feeds the rigorous bf16-error margin.
// ---------------------------------------------------------------------------
__global__ __launch_bounds__(256) void kemax_kernel(
    const float* __restrict__ Kf, float* __restrict__ kemax)
{
  const int bh = blockIdx.x;
  const int b = bh >> 3, h = bh & 7;
  const int e = threadIdx.x & 63, chunk = threadIdx.x >> 6;
  const float* base = Kf + ((size_t)b * SEQ_L) * D_MODEL + h * HEAD_E + e;
  float mx = 0.f;
  for (int k = chunk * 512; k < chunk * 512 + 512; ++k)
    mx = fmaxf(mx, fabsf(base[(size_t)k * D_MODEL]));
  __shared__ float red[4][64];
  red[chunk][e] = mx;
  __syncthreads();
  if (threadIdx.x < 64) {
    float m0 = fmaxf(fmaxf(red[0][threadIdx.x], red[1][threadIdx.x]),
                     fmaxf(red[2][threadIdx.x], red[3][threadIdx.x]));
    kemax[bh * 64 + threadIdx.x] = m0;
  }
}

// ---------------------------------------------------------------------------
// Fused ProbSparse attention v8 — MFMA bf16 score scan + provable-margin
// capture; candidate OVERFLOW (> CCAP) now falls back to an exact f32
// rescan of all 2048 keys (no truncation anywhere). Then exact bisect to
// [40,64] -> compact -> bitonic sort -> gap test (3e-4) -> shuffle-only
// exact-f64 rescore fallback -> softmax -> PV.
// grid (L/16, B*H), block 512 = 8 waves; wave w owns queries 2w, 2w+1.
// ---------------------------------------------------------------------------
__global__ __launch_bounds__(512) void attn_kernel(
    const float* __restrict__ Qf, const float* __restrict__ Kf,
    const float* __restrict__ Vf,
    const unsigned short* __restrict__ Qh, const unsigned short* __restrict__ Kh,
    const float* __restrict__ kemax,
    const float* __restrict__ x,
    const float* __restrict__ Wq, const float* __restrict__ bq,
    const float* __restrict__ Wk, const float* __restrict__ bk,
    float* __restrict__ AO)
{
  __shared__ __half  S[16][SP];          // 65600 B approx scores
  __shared__ float   cvs2[8][CCAP];      // captured candidate approx values
  __shared__ short   cis2[8][CCAP];      // captured candidate indices
  __shared__ float   cvs[8][64];         // exact candidates (post bisect)
  __shared__ short   cis[8][64];
  __shared__ float   qrowL[8][64];       // per-wave f32 q row
  __shared__ float   kemaxL[64];

  const int t    = threadIdx.x;
  const int w    = t >> 6;
  const int l    = t & 63;
  const int bh   = blockIdx.y;
  const int b    = bh >> 3, h = bh & 7;
  const int q0   = blockIdx.x << 4;
  const size_t rowbase = (size_t)b * SEQ_L;

  if (t < 64) kemaxL[t] = kemax[bh * 64 + t];

  // ---- MFMA score scan: wave w covers keys [w*256, w*256+256) ----
  {
    const int lo16 = l & 15, grp = l >> 4;
    const unsigned short* qrow =
        Qh + (rowbase + q0 + lo16) * D_MODEL + h * HEAD_E;
    bf16x8 a0 = *(const bf16x8*)&qrow[grp * 8];
    bf16x8 a1 = *(const bf16x8*)&qrow[32 + grp * 8];

    const int kbase = w * 256;
#pragma unroll
    for (int kt = 0; kt < 4; ++kt) {
#pragma unroll
      for (int kc = 0; kc < 4; ++kc) {
        const int key0 = kbase + kt * 64 + kc * 16 + lo16;
        const unsigned short* krow =
            Kh + (rowbase + key0) * D_MODEL + h * HEAD_E;
        bf16x8 b0 = *(const bf16x8*)&krow[grp * 8];
        bf16x8 b1 = *(const bf16x8*)&krow[32 + grp * 8];
        f32x4 acc = {0.f, 0.f, 0.f, 0.f};
        acc = __builtin_amdgcn_mfma_f32_16x16x32_bf16(a0, b0, acc, 0, 0, 0);
        acc = __builtin_amdgcn_mfma_f32_16x16x32_bf16(a1, b1, acc, 0, 0, 0);
#pragma unroll
        for (int r = 0; r < 4; ++r)
          S[grp * 4 + r][key0] = __float2half(acc[r] * 0.125f);
      }
    }
  }
  __syncthreads();

  // ---- selection: wave w handles queries 2w, 2w+1 ----
  for (int qq = 0; qq < 2; ++qq) {
    const int q = 2 * w + qq;

    qrowL[w][l] = Qf[(rowbase + q0 + q) * D_MODEL + h * HEAD_E + l];

    float v[32];
#pragma unroll
    for (int j = 0; j < 32; ++j) v[j] = __half2float(S[q][(j << 6) + l]);

    float m = v[0];
#pragma unroll
    for (int j = 1; j < 32; ++j) m = fmaxf(m, v[j]);
#pragma unroll
    for (int off = 1; off < 64; off <<= 1) m = fmaxf(m, __shfl_xor(m, off));

    auto countge = [&](float T) -> int {
      int c = 0;
#pragma unroll
      for (int j = 0; j < 32; ++j) c += (v[j] >= T) ? 1 : 0;
#pragma unroll
      for (int off = 1; off < 64; off <<= 1) c += __shfl_xor(c, off);
      return c;
    };

    // approx bisect: count(>=lo) in [40, 64] (>=40 guaranteed)
    float lo = m - 0.5f;
    int C = countge(lo);
    float step = 1.0f;
    while (C < 40) {
      lo -= step; step *= 2.0f;
      if (step > 1.0e30f) { lo = -3.0e38f; C = 2048; break; }
      C = countge(lo);
    }
    float hi = m;
    for (int it = 0; it < 24 && C > 64; ++it) {
      float mid = 0.5f * (lo + hi);
      int cm = countge(mid);
      if (cm >= 40) { lo = mid; C = cm; } else hi = mid;
    }

    // provable margin: |approx-exact| <= red*2^-10 + f16store; capture 2x.
    float red = fabsf(qrowL[w][l]) * kemaxL[l];
#pragma unroll
    for (int off = 1; off < 64; off <<= 1) red += __shfl_xor(red, off);
    const float lo2 = lo - (red * 0.0025f + 0.008f);

    // capture candidates (approx >= lo2) in key order
    int base = 0;
#pragma unroll
    for (int j = 0; j < 32; ++j) {
      bool in = (v[j] >= lo2);
      unsigned long long mk = __ballot(in);
      if (in) {
        int pos = base + (int)__popcll(mk & ((1ull << l) - 1ull));
        if (pos < CCAP) { cvs2[w][pos] = v[j]; cis2[w][pos] = (short)((j << 6) + l); }
      }
      base += (int)__popcll(mk);
    }

    int C2;
    if (base <= CCAP) {
      // ---- common path: exact f32 rescore of captured candidates ----
      const int count2 = base;
      const int i0 = l, i1 = 64 + l, i2 = 128 + l;
      const int idx0 = (i0 < count2) ? (int)cis2[w][i0] : 0;
      const int idx1 = (i1 < count2) ? (int)cis2[w][i1] : 0;
      const int idx2 = (i2 < count2) ? (int)cis2[w][i2] : 0;
      float e0 = -3.0e38f, e1 = -3.0e38f, e2 = -3.0e38f;
      {
        const float* kr0 = Kf + (rowbase + idx0) * D_MODEL + h * HEAD_E;
        const float* kr1 = Kf + (rowbase + idx1) * D_MODEL + h * HEAD_E;
        const float* kr2 = Kf + (rowbase + idx2) * D_MODEL + h * HEAD_E;
        float r0 = 0.f, r1 = 0.f, r2 = 0.f;
#pragma unroll
        for (int e4 = 0; e4 < 16; ++e4) {
          float4 qv = *(const float4*)&qrowL[w][e4 * 4];
          float4 k0 = *(const float4*)&kr0[e4 * 4];
          float4 k1 = *(const float4*)&kr1[e4 * 4];
          float4 k2 = *(const float4*)&kr2[e4 * 4];
          r0 += qv.x * k0.x + qv.y * k0.y + qv.z * k0.z + qv.w * k0.w;
          r1 += qv.x * k1.x + qv.y * k1.y + qv.z * k1.z + qv.w * k1.w;
          r2 += qv.x * k2.x + qv.y * k2.y + qv.z * k2.z + qv.w * k2.w;
        }
        if (i0 < count2) e0 = r0 * 0.125f;
        if (i1 < count2) e1 = r1 * 0.125f;
        if (i2 < count2) e2 = r2 * 0.125f;
      }

      // exact bisect to count in [40, 64]
      float hiv = fmaxf(fmaxf(e0, e1), e2);
      float lov = fminf(fminf((i0 < count2) ? e0 : 3.0e38f,
                              (i1 < count2) ? e1 : 3.0e38f),
                              (i2 < count2) ? e2 : 3.0e38f);
#pragma unroll
      for (int off = 1; off < 64; off <<= 1) {
        hiv = fmaxf(hiv, __shfl_xor(hiv, off));
        lov = fminf(lov, __shfl_xor(lov, off));
      }
      lov -= 1e-3f;
      for (int it = 0; it < 30; ++it) {
        int c = (int)__popcll(__ballot(e0 >= lov)) +
                (int)__popcll(__ballot(e1 >= lov)) +
                (int)__popcll(__ballot(e2 >= lov));
        if (c <= 64) break;
        float mid = 0.5f * (lov + hiv);
        int cm = (int)__popcll(__ballot(e0 >= mid)) +
                 (int)__popcll(__ballot(e1 >= mid)) +
                 (int)__popcll(__ballot(e2 >= mid));
        if (cm >= 40) lov = mid; else hiv = mid;
      }

      // compact exact-selected into cvs/cis (key order preserved)
      bool in0 = (e0 >= lov);
      bool in1 = (e1 >= lov);
      bool in2 = (e2 >= lov);
      unsigned long long m0 = __ballot(in0);
      unsigned long long m1 = __ballot(in1);
      unsigned long long m2 = __ballot(in2);
      int tot0 = (int)__popcll(m0), tot1 = (int)__popcll(m1);
      if (in0) {
        int p = (int)__popcll(m0 & ((1ull << l) - 1ull));
        if (p < 64) { cvs[w][p] = e0; cis[w][p] = (short)idx0; }
      }
      if (in1) {
        int p = tot0 + (int)__popcll(m1 & ((1ull << l) - 1ull));
        if (p < 64) { cvs[w][p] = e1; cis[w][p] = (short)idx1; }
      }
      if (in2) {
        int p = tot0 + tot1 + (int)__popcll(m2 & ((1ull << l) - 1ull));
        if (p < 64) { cvs[w][p] = e2; cis[w][p] = (short)idx2; }
      }
      int tot = tot0 + tot1 + (int)__popcll(m2);
      C2 = (tot < 64) ? tot : 64;
    } else {
      // ---- rare overflow path: exact f32 rescan of ALL keys (no cap) ----
#pragma unroll 4
      for (int j = 0; j < 32; ++j) {
        const float* kr = Kf + (rowbase + (j << 6) + l) * D_MODEL + h * HEAD_E;
        float r0 = 0.f, r1 = 0.f;
#pragma unroll
        for (int e4 = 0; e4 < 16; e4 += 2) {
          float4 qv0 = *(const float4*)&qrowL[w][e4 * 4];
          float4 qv1 = *(const float4*)&qrowL[w][e4 * 4 + 4];
          float4 k0 = *(const float4*)&kr[e4 * 4];
          float4 k1 = *(const float4*)&kr[e4 * 4 + 4];
          r0 += qv0.x * k0.x + qv0.y * k0.y + qv0.z * k0.z + qv0.w * k0.w;
          r1 += qv1.x * k1.x + qv1.y * k1.y + qv1.z * k1.z + qv1.w * k1.w;
        }
        v[j] = (r0 + r1) * 0.125f;   // v now holds EXACT f32 scores
      }
      // exact bisect on full score set to [40, 64]
      float hiv = v[0], lov = v[0];
#pragma unroll
      for (int j = 1; j < 32; ++j) {
        hiv = fmaxf(hiv, v[j]); lov = fminf(lov, v[j]);
      }
#pragma unroll
      for (int off = 1; off < 64; off <<= 1) {
        hiv = fmaxf(hiv, __shfl_xor(hiv, off));
        lov = fminf(lov, __shfl_xor(lov, off));
      }
      lov -= 1e-3f;
      for (int it = 0; it < 30; ++it) {
        int c = countge(lov);
        if (c <= 64) break;
        float mid = 0.5f * (lov + hiv);
        int cm = countge(mid);
        if (cm >= 40) lov = mid; else hiv = mid;
      }
      int bb = 0;
#pragma unroll
      for (int j = 0; j < 32; ++j) {
        bool in = (v[j] >= lov);
        unsigned long long mk = __ballot(in);
        if (in) {
          int pos = bb + (int)__popcll(mk & ((1ull << l) - 1ull));
          if (pos < 64) { cvs[w][pos] = v[j]; cis[w][pos] = (short)((j << 6) + l); }
        }
        bb += (int)__popcll(mk);
      }
      C2 = (bb < 64) ? bb : 64;
    }

    float cval = (l < C2) ? cvs[w][l] : -3.0e38f;
    int   cidx = (l < C2) ? (int)cis[w][l] : (2 * SEQ_L + l);

    // bitonic sort 64: value desc, index asc
#pragma unroll
    for (int sz = 2; sz <= 64; sz <<= 1) {
#pragma unroll
      for (int st = sz >> 1; st >= 1; st >>= 1) {
        float ov = __shfl_xor(cval, st);
        int   oi = __shfl_xor(cidx, st);
        bool ob    = (ov > cval) || ((ov == cval) && (oi < cidx));
        bool dir   = ((l & sz) == 0);
        bool lower = ((l & st) == 0);
        if (ob == (lower == dir)) { cval = ov; cidx = oi; }
      }
    }

    const float m_ex = __shfl(cval, 0);
    const float v37  = __shfl(cval, 37);
    const float v38  = __shfl(cval, 38);
    const bool tight = (v37 - v38 < 3e-4f);

    float myw;
    if (!tight) {
      myw = (l < KSEL) ? __expf(cval - m_ex) : 0.f;
    } else {
      // exact f64 rescore, shuffle-only: s = sum_e qd_e*bk_e
      //   + sum_j u_j * x[c][j],  u_j = sum_e qd_e * Wk[h*64+e][j]
      const int he = h * HEAD_E + l;
      const float* wqr = Wq + (size_t)he * D_MODEL;
      const float* xr  = x + (rowbase + q0 + q) * D_MODEL;
      double qd = 0.0;
      for (int j = 0; j < D_MODEL; ++j) qd += (double)wqr[j] * (double)xr[j];
      qd += (double)bq[he];                      // qd = Q[qrow][he] exact f64

      double qkb = qd * (double)bk[he];
#pragma unroll
      for (int off = 1; off < 64; off <<= 1) qkb += __shfl_xor(qkb, off);

      const int crow = (l < C2) ? cidx : 0;
      const float* xc = x + (rowbase + crow) * D_MODEL;
      double s_c = qkb;
      for (int jc = 0; jc < 8; ++jc) {
        const float* wkc = Wk + (jc << 6) + l;
        double uacc = 0.0;
        for (int e = 0; e < 64; ++e) {
          double qde = __shfl(qd, e);
          uacc += qde * (double)wkc[(size_t)(h * HEAD_E + e) * D_MODEL];
        }
        for (int jj = 0; jj < 64; ++jj) {
          double ujj = __shfl(uacc, jj);
          s_c += ujj * (double)xc[(jc << 6) + jj];
        }
      }
      double d = (l < C2) ? s_c * 0.125 : -1.0e300;
      int myi = (l < C2) ? cidx : (2 * SEQ_L + l);
      double mxd = -1.0e300; int rank = 0;
      for (int j = 0; j < 64; ++j) {
        double dj = __shfl(d, j);
        int    ij = __shfl(myi, j);
        if (dj > mxd) mxd = dj;
        rank += (dj > d) || ((dj == d) && (ij < myi));
      }
      myw = (l < C2 && rank < KSEL) ? __expf((float)(d - mxd)) : 0.f;
    }

    float psum = myw;
#pragma unroll
    for (int off = 1; off < 64; off <<= 1) psum += __shfl_xor(psum, off);
    const float inv = 1.0f / psum;

    // PV: lane = head dim
    const float* Vb = Vf + rowbase * D_MODEL + h * HEAD_E;
    float acc = 0.f;
    const int nn = tight ? 64 : KSEL;
    for (int j = 0; j < nn; ++j) {
      float wj = __shfl(myw, j);
      if (wj != 0.f) {
        int sj = __shfl(cidx, j);
        acc += wj * Vb[(size_t)sj * D_MODEL + l];
      }
    }
    AO[(rowbase + q0 + q) * D_MODEL + h * HEAD_E + l] = acc * inv;
  }
}

// ---------------------------------------------------------------------------
extern "C" void kernel_launch(void* const* d_in, const int* in_sizes, int n_in,
                              void* d_out, int out_size, void* d_ws, size_t ws_size,
                              hipStream_t stream) {
  const float* x  = (const float*)d_in[0];
  const float* Wq = (const float*)d_in[1];
  const float* bq = (const float*)d_in[2];
  const float* Wk = (const float*)d_in[3];
  const float* bk = (const float*)d_in[4];
  const float* Wv = (const float*)d_in[5];
  const float* bv = (const float*)d_in[6];
  const float* Wo = (const float*)d_in[7];
  const float* bo = (const float*)d_in[8];
  float* out = (float*)d_out;

  char* ws = (char*)d_ws;
  const size_t MATB = (size_t)M_ROWS * D_MODEL * 4;  // 8 MB
  float* Qf = (float*)ws;
  float* Kf = (float*)(ws + MATB);
  float* Vf = (float*)(ws + 2 * MATB);
  float* AO = (float*)(ws + 3 * MATB);
  unsigned short* Qh = (unsigned short*)(ws + 4 * MATB);            // 4 MB
  unsigned short* Kh = (unsigned short*)(ws + 4 * MATB + MATB / 2); // 4 MB
  float* kemax = (float*)(ws + 5 * MATB);                           // 4 KB

  dim3 qkvgrid(D_MODEL / 64, M_ROWS / 64, 3);
  gemm_qkv_kernel<<<qkvgrid, 256, 0, stream>>>(
      x, Wq, bq, Wk, bk, Wv, bv, Qf, Kf, Vf, Qh, Kh);

  kemax_kernel<<<dim3(BATCH * N_HEADS), 256, 0, stream>>>(Kf, kemax);

  attn_kernel<<<dim3(SEQ_L / 16, BATCH * N_HEADS), 512, 0, stream>>>(
      Qf, Kf, Vf, Qh, Kh, kemax, x, Wq, bq, Wk, bk, AO);

  dim3 ggrid(D_MODEL / 64, M_ROWS / 64);
  gemm_bias_kernel<<<ggrid, 256, 0, stream>>>(AO, Wo, bo, out, M_ROWS, D_MODEL, D_MODEL);
}

// Round 9
// 1112.075 us; speedup vs baseline: 9.1079x; 1.1789x over previous
//
#include <hip/hip_runtime.h>
#include <hip/hip_fp16.h>
#include <cstdint>
#include <cstddef>

#define D_MODEL 512
#define N_HEADS 8
#define HEAD_E  64
#define SEQ_L   2048
#define BATCH   2
#define KSEL    38            // int(5*log(2048)) = 38
#define M_ROWS  (BATCH*SEQ_L) // 4096
#define SP      2050          // S row stride (f16): odd dword stride de-banks rows
#define CCAP    192           // candidate cap (3 per lane); overflow -> exact rescan

typedef short bf16x8 __attribute__((ext_vector_type(8)));
typedef float f32x4  __attribute__((ext_vector_type(4)));

static __device__ __forceinline__ unsigned short f2bf(float x) {
  uint32_t u = __float_as_uint(x);
  return (unsigned short)((u + 0x7FFF + ((u >> 16) & 1)) >> 16);  // RNE
}

// ---------------------------------------------------------------------------
// Fused QKV f32 GEMM: z=0:Q, z=1:K, z=2:V. C = x @ W.T + b.
// Q,K also emit bf16 copies for the MFMA score scan.
// ---------------------------------------------------------------------------
__global__ __launch_bounds__(256) void gemm_qkv_kernel(
    const float* __restrict__ A,
    const float* __restrict__ Wq, const float* __restrict__ bq,
    const float* __restrict__ Wk, const float* __restrict__ bk,
    const float* __restrict__ Wv, const float* __restrict__ bv,
    float* __restrict__ Qf, float* __restrict__ Kf, float* __restrict__ Vf,
    unsigned short* __restrict__ Qh, unsigned short* __restrict__ Kh)
{
  const int z = blockIdx.z;
  const float* W    = (z == 0) ? Wq : ((z == 1) ? Wk : Wv);
  const float* bias = (z == 0) ? bq : ((z == 1) ? bk : bv);
  float* C          = (z == 0) ? Qf : ((z == 1) ? Kf : Vf);
  unsigned short* Ch = (z == 0) ? Qh : ((z == 1) ? Kh : nullptr);

  __shared__ float As[64][36];
  __shared__ float Ws[64][36];
  const int t  = threadIdx.x;
  const int tx = t & 15, ty = t >> 4;
  const int bm = blockIdx.y << 6, bn = blockIdx.x << 6;

  float acc[4][4] = {};

  for (int k0 = 0; k0 < D_MODEL; k0 += 32) {
    __syncthreads();
#pragma unroll
    for (int i = 0; i < 2; ++i) {
      int f = t + (i << 8);
      int r = f >> 3, c = (f & 7) << 2;
      *(float4*)&As[r][c] = *(const float4*)&A[(size_t)(bm + r) * D_MODEL + k0 + c];
      *(float4*)&Ws[r][c] = *(const float4*)&W[(size_t)(bn + r) * D_MODEL + k0 + c];
    }
    __syncthreads();
#pragma unroll
    for (int kk = 0; kk < 32; kk += 4) {
      float4 av[4], wv[4];
#pragma unroll
      for (int i = 0; i < 4; ++i) av[i] = *(const float4*)&As[ty * 4 + i][kk];
#pragma unroll
      for (int j = 0; j < 4; ++j) wv[j] = *(const float4*)&Ws[tx + 16 * j][kk];
#pragma unroll
      for (int i = 0; i < 4; ++i)
#pragma unroll
        for (int j = 0; j < 4; ++j)
          acc[i][j] += av[i].x * wv[j].x + av[i].y * wv[j].y +
                       av[i].z * wv[j].z + av[i].w * wv[j].w;
    }
  }

#pragma unroll
  for (int i = 0; i < 4; ++i) {
    int row = bm + ty * 4 + i;
#pragma unroll
    for (int j = 0; j < 4; ++j) {
      int col = bn + tx + 16 * j;
      float v = acc[i][j] + bias[col];
      size_t idx = (size_t)row * D_MODEL + col;
      C[idx] = v;
      if (Ch) Ch[idx] = f2bf(v);
    }
  }
}

// ---------------------------------------------------------------------------
// f32 GEMM (output projection): C = A @ W.T + b
// ---------------------------------------------------------------------------
__global__ __launch_bounds__(256) void gemm_bias_kernel(
    const float* __restrict__ A, const float* __restrict__ W,
    const float* __restrict__ bias, float* __restrict__ C,
    int M, int N, int K)
{
  __shared__ float As[64][36];
  __shared__ float Ws[64][36];
  const int t  = threadIdx.x;
  const int tx = t & 15, ty = t >> 4;
  const int bm = blockIdx.y << 6, bn = blockIdx.x << 6;

  float acc[4][4] = {};

  for (int k0 = 0; k0 < K; k0 += 32) {
    __syncthreads();
#pragma unroll
    for (int i = 0; i < 2; ++i) {
      int f = t + (i << 8);
      int r = f >> 3, c = (f & 7) << 2;
      *(float4*)&As[r][c] = *(const float4*)&A[(size_t)(bm + r) * K + k0 + c];
      *(float4*)&Ws[r][c] = *(const float4*)&W[(size_t)(bn + r) * K + k0 + c];
    }
    __syncthreads();
#pragma unroll
    for (int kk = 0; kk < 32; kk += 4) {
      float4 av[4], wv[4];
#pragma unroll
      for (int i = 0; i < 4; ++i) av[i] = *(const float4*)&As[ty * 4 + i][kk];
#pragma unroll
      for (int j = 0; j < 4; ++j) wv[j] = *(const float4*)&Ws[tx + 16 * j][kk];
#pragma unroll
      for (int i = 0; i < 4; ++i)
#pragma unroll
        for (int j = 0; j < 4; ++j)
          acc[i][j] += av[i].x * wv[j].x + av[i].y * wv[j].y +
                       av[i].z * wv[j].z + av[i].w * wv[j].w;
    }
  }

#pragma unroll
  for (int i = 0; i < 4; ++i) {
    int row = bm + ty * 4 + i;
#pragma unroll
    for (int j = 0; j < 4; ++j) {
      int col = bn + tx + 16 * j;
      C[(size_t)row * N + col] = acc[i][j] + bias[col];
    }
  }
}

// ---------------------------------------------------------------------------
// Per-(b,h,e) max |K_e| over keys — feeds the rigorous bf16-error margin.
// ---------------------------------------------------------------------------
__global__ __launch_bounds__(256) void kemax_kernel(
    const float* __restrict__ Kf, float* __restrict__ kemax)
{
  const int bh = blockIdx.x;
  const int b = bh >> 3, h = bh & 7;
  const int e = threadIdx.x & 63, chunk = threadIdx.x >> 6;
  const float* base = Kf + ((size_t)b * SEQ_L) * D_MODEL + h * HEAD_E + e;
  float mx = 0.f;
  for (int k = chunk * 512; k < chunk * 512 + 512; ++k)
    mx = fmaxf(mx, fabsf(base[(size_t)k * D_MODEL]));
  __shared__ float red[4][64];
  red[chunk][e] = mx;
  __syncthreads();
  if (threadIdx.x < 64) {
    float m0 = fmaxf(fmaxf(red[0][threadIdx.x], red[1][threadIdx.x]),
                     fmaxf(red[2][threadIdx.x], red[3][threadIdx.x]));
    kemax[bh * 64 + threadIdx.x] = m0;
  }
}

// ---------------------------------------------------------------------------
// Fused ProbSparse attention v9 — v8 machinery (proven) + latency fixes:
//  * XCD-affine 1D grid: xcd = wg&7 pinned to one (b,h) at a time so the
//    K/V slice (~1MB) stays resident in that XCD's private L2.
//  * Branchless PV unrolled x8: 8 gather loads in flight (was 1 behind a
//    wave-uniform branch).
//  * Dead cvs2 value array removed (capture keeps indices only).
// grid 2048 x 512thr = 8 waves; wave w owns queries 2w, 2w+1 of a 16-query
// block. Selection math byte-identical to v8.
// ---------------------------------------------------------------------------
__global__ __launch_bounds__(512) void attn_kernel(
    const float* __restrict__ Qf, const float* __restrict__ Kf,
    const float* __restrict__ Vf,
    const unsigned short* __restrict__ Qh, const unsigned short* __restrict__ Kh,
    const float* __restrict__ kemax,
    const float* __restrict__ x,
    const float* __restrict__ Wq, const float* __restrict__ bq,
    const float* __restrict__ Wk, const float* __restrict__ bk,
    float* __restrict__ AO)
{
  __shared__ __half  S[16][SP];          // 65600 B approx scores
  __shared__ short   cis2[8][CCAP];      // captured candidate indices
  __shared__ float   cvs[8][64];         // exact candidates (post bisect)
  __shared__ short   cis[8][64];
  __shared__ float   qrowL[8][64];       // per-wave f32 q row
  __shared__ float   kemaxL[64];

  const int t    = threadIdx.x;
  const int w    = t >> 6;
  const int l    = t & 63;

  // XCD-affine decode: round-robin dispatch puts wg&7 on XCD (wg&7).
  const int wg   = blockIdx.x;
  const int xcd  = wg & 7;
  const int idx  = wg >> 3;              // 0..255
  const int bh   = xcd + 8 * (idx >> 7); // XCD handles bh, then bh+8
  const int qblk = idx & 127;
  const int b    = bh >> 3, h = bh & 7;
  const int q0   = qblk << 4;
  const size_t rowbase = (size_t)b * SEQ_L;

  if (t < 64) kemaxL[t] = kemax[bh * 64 + t];

  // ---- MFMA score scan: wave w covers keys [w*256, w*256+256) ----
  {
    const int lo16 = l & 15, grp = l >> 4;
    const unsigned short* qrow =
        Qh + (rowbase + q0 + lo16) * D_MODEL + h * HEAD_E;
    bf16x8 a0 = *(const bf16x8*)&qrow[grp * 8];
    bf16x8 a1 = *(const bf16x8*)&qrow[32 + grp * 8];

    const int kbase = w * 256;
#pragma unroll
    for (int kt = 0; kt < 4; ++kt) {
#pragma unroll
      for (int kc = 0; kc < 4; ++kc) {
        const int key0 = kbase + kt * 64 + kc * 16 + lo16;
        const unsigned short* krow =
            Kh + (rowbase + key0) * D_MODEL + h * HEAD_E;
        bf16x8 b0 = *(const bf16x8*)&krow[grp * 8];
        bf16x8 b1 = *(const bf16x8*)&krow[32 + grp * 8];
        f32x4 acc = {0.f, 0.f, 0.f, 0.f};
        acc = __builtin_amdgcn_mfma_f32_16x16x32_bf16(a0, b0, acc, 0, 0, 0);
        acc = __builtin_amdgcn_mfma_f32_16x16x32_bf16(a1, b1, acc, 0, 0, 0);
#pragma unroll
        for (int r = 0; r < 4; ++r)
          S[grp * 4 + r][key0] = __float2half(acc[r] * 0.125f);
      }
    }
  }
  __syncthreads();

  // ---- selection: wave w handles queries 2w, 2w+1 ----
  for (int qq = 0; qq < 2; ++qq) {
    const int q = 2 * w + qq;

    qrowL[w][l] = Qf[(rowbase + q0 + q) * D_MODEL + h * HEAD_E + l];

    float v[32];
#pragma unroll
    for (int j = 0; j < 32; ++j) v[j] = __half2float(S[q][(j << 6) + l]);

    float m = v[0];
#pragma unroll
    for (int j = 1; j < 32; ++j) m = fmaxf(m, v[j]);
#pragma unroll
    for (int off = 1; off < 64; off <<= 1) m = fmaxf(m, __shfl_xor(m, off));

    auto countge = [&](float T) -> int {
      int c = 0;
#pragma unroll
      for (int j = 0; j < 32; ++j) c += (v[j] >= T) ? 1 : 0;
#pragma unroll
      for (int off = 1; off < 64; off <<= 1) c += __shfl_xor(c, off);
      return c;
    };

    // approx bisect: count(>=lo) in [40, 64] (>=40 guaranteed)
    float lo = m - 0.5f;
    int C = countge(lo);
    float step = 1.0f;
    while (C < 40) {
      lo -= step; step *= 2.0f;
      if (step > 1.0e30f) { lo = -3.0e38f; C = 2048; break; }
      C = countge(lo);
    }
    float hi = m;
    for (int it = 0; it < 24 && C > 64; ++it) {
      float mid = 0.5f * (lo + hi);
      int cm = countge(mid);
      if (cm >= 40) { lo = mid; C = cm; } else hi = mid;
    }

    // provable margin (bf16 RNE + f16 store + mfma accum), 2x slack
    float red = fabsf(qrowL[w][l]) * kemaxL[l];
#pragma unroll
    for (int off = 1; off < 64; off <<= 1) red += __shfl_xor(red, off);
    const float lo2 = lo - (red * 0.0025f + 0.008f);

    // capture candidate indices (approx >= lo2) in key order
    int base = 0;
#pragma unroll
    for (int j = 0; j < 32; ++j) {
      bool in = (v[j] >= lo2);
      unsigned long long mk = __ballot(in);
      if (in) {
        int pos = base + (int)__popcll(mk & ((1ull << l) - 1ull));
        if (pos < CCAP) cis2[w][pos] = (short)((j << 6) | l);
      }
      base += (int)__popcll(mk);
    }

    int C2;
    if (base <= CCAP) {
      // ---- common path: exact f32 rescore of captured candidates ----
      const int count2 = base;
      const int i0 = l, i1 = 64 + l, i2 = 128 + l;
      const int idx0 = (i0 < count2) ? (int)cis2[w][i0] : 0;
      const int idx1 = (i1 < count2) ? (int)cis2[w][i1] : 0;
      const int idx2 = (i2 < count2) ? (int)cis2[w][i2] : 0;
      float e0 = -3.0e38f, e1 = -3.0e38f, e2 = -3.0e38f;
      {
        const float* kr0 = Kf + (rowbase + idx0) * D_MODEL + h * HEAD_E;
        const float* kr1 = Kf + (rowbase + idx1) * D_MODEL + h * HEAD_E;
        const float* kr2 = Kf + (rowbase + idx2) * D_MODEL + h * HEAD_E;
        float r0 = 0.f, r1 = 0.f, r2 = 0.f;
#pragma unroll
        for (int e4 = 0; e4 < 16; ++e4) {
          float4 qv = *(const float4*)&qrowL[w][e4 * 4];
          float4 k0 = *(const float4*)&kr0[e4 * 4];
          float4 k1 = *(const float4*)&kr1[e4 * 4];
          float4 k2 = *(const float4*)&kr2[e4 * 4];
          r0 += qv.x * k0.x + qv.y * k0.y + qv.z * k0.z + qv.w * k0.w;
          r1 += qv.x * k1.x + qv.y * k1.y + qv.z * k1.z + qv.w * k1.w;
          r2 += qv.x * k2.x + qv.y * k2.y + qv.z * k2.z + qv.w * k2.w;
        }
        if (i0 < count2) e0 = r0 * 0.125f;
        if (i1 < count2) e1 = r1 * 0.125f;
        if (i2 < count2) e2 = r2 * 0.125f;
      }

      // exact bisect to count in [40, 64]
      float hiv = fmaxf(fmaxf(e0, e1), e2);
      float lov = fminf(fminf((i0 < count2) ? e0 : 3.0e38f,
                              (i1 < count2) ? e1 : 3.0e38f),
                              (i2 < count2) ? e2 : 3.0e38f);
#pragma unroll
      for (int off = 1; off < 64; off <<= 1) {
        hiv = fmaxf(hiv, __shfl_xor(hiv, off));
        lov = fminf(lov, __shfl_xor(lov, off));
      }
      lov -= 1e-3f;
      for (int it = 0; it < 30; ++it) {
        int c = (int)__popcll(__ballot(e0 >= lov)) +
                (int)__popcll(__ballot(e1 >= lov)) +
                (int)__popcll(__ballot(e2 >= lov));
        if (c <= 64) break;
        float mid = 0.5f * (lov + hiv);
        int cm = (int)__popcll(__ballot(e0 >= mid)) +
                 (int)__popcll(__ballot(e1 >= mid)) +
                 (int)__popcll(__ballot(e2 >= mid));
        if (cm >= 40) lov = mid; else hiv = mid;
      }

      // compact exact-selected into cvs/cis (key order preserved)
      bool in0 = (e0 >= lov);
      bool in1 = (e1 >= lov);
      bool in2 = (e2 >= lov);
      unsigned long long m0 = __ballot(in0);
      unsigned long long m1 = __ballot(in1);
      unsigned long long m2 = __ballot(in2);
      int tot0 = (int)__popcll(m0), tot1 = (int)__popcll(m1);
      if (in0) {
        int p = (int)__popcll(m0 & ((1ull << l) - 1ull));
        if (p < 64) { cvs[w][p] = e0; cis[w][p] = (short)idx0; }
      }
      if (in1) {
        int p = tot0 + (int)__popcll(m1 & ((1ull << l) - 1ull));
        if (p < 64) { cvs[w][p] = e1; cis[w][p] = (short)idx1; }
      }
      if (in2) {
        int p = tot0 + tot1 + (int)__popcll(m2 & ((1ull << l) - 1ull));
        if (p < 64) { cvs[w][p] = e2; cis[w][p] = (short)idx2; }
      }
      int tot = tot0 + tot1 + (int)__popcll(m2);
      C2 = (tot < 64) ? tot : 64;
    } else {
      // ---- rare overflow path: exact f32 rescan of ALL keys (no cap) ----
#pragma unroll 4
      for (int j = 0; j < 32; ++j) {
        const float* kr = Kf + (rowbase + (j << 6) + l) * D_MODEL + h * HEAD_E;
        float r0 = 0.f, r1 = 0.f;
#pragma unroll
        for (int e4 = 0; e4 < 16; e4 += 2) {
          float4 qv0 = *(const float4*)&qrowL[w][e4 * 4];
          float4 qv1 = *(const float4*)&qrowL[w][e4 * 4 + 4];
          float4 k0 = *(const float4*)&kr[e4 * 4];
          float4 k1 = *(const float4*)&kr[e4 * 4 + 4];
          r0 += qv0.x * k0.x + qv0.y * k0.y + qv0.z * k0.z + qv0.w * k0.w;
          r1 += qv1.x * k1.x + qv1.y * k1.y + qv1.z * k1.z + qv1.w * k1.w;
        }
        v[j] = (r0 + r1) * 0.125f;   // v now holds EXACT f32 scores
      }
      float hiv = v[0], lov = v[0];
#pragma unroll
      for (int j = 1; j < 32; ++j) {
        hiv = fmaxf(hiv, v[j]); lov = fminf(lov, v[j]);
      }
#pragma unroll
      for (int off = 1; off < 64; off <<= 1) {
        hiv = fmaxf(hiv, __shfl_xor(hiv, off));
        lov = fminf(lov, __shfl_xor(lov, off));
      }
      lov -= 1e-3f;
      for (int it = 0; it < 30; ++it) {
        int c = countge(lov);
        if (c <= 64) break;
        float mid = 0.5f * (lov + hiv);
        int cm = countge(mid);
        if (cm >= 40) lov = mid; else hiv = mid;
      }
      int bb = 0;
#pragma unroll
      for (int j = 0; j < 32; ++j) {
        bool in = (v[j] >= lov);
        unsigned long long mk = __ballot(in);
        if (in) {
          int pos = bb + (int)__popcll(mk & ((1ull << l) - 1ull));
          if (pos < 64) { cvs[w][pos] = v[j]; cis[w][pos] = (short)((j << 6) + l); }
        }
        bb += (int)__popcll(mk);
      }
      C2 = (bb < 64) ? bb : 64;
    }

    float cval = (l < C2) ? cvs[w][l] : -3.0e38f;
    int   cidx = (l < C2) ? (int)cis[w][l] : (2 * SEQ_L + l);

    // bitonic sort 64: value desc, index asc
#pragma unroll
    for (int sz = 2; sz <= 64; sz <<= 1) {
#pragma unroll
      for (int st = sz >> 1; st >= 1; st >>= 1) {
        float ov = __shfl_xor(cval, st);
        int   oi = __shfl_xor(cidx, st);
        bool ob    = (ov > cval) || ((ov == cval) && (oi < cidx));
        bool dir   = ((l & sz) == 0);
        bool lower = ((l & st) == 0);
        if (ob == (lower == dir)) { cval = ov; cidx = oi; }
      }
    }

    const float m_ex = __shfl(cval, 0);
    const float v37  = __shfl(cval, 37);
    const float v38  = __shfl(cval, 38);
    const bool tight = (v37 - v38 < 3e-4f);

    float myw;
    if (!tight) {
      myw = (l < KSEL) ? __expf(cval - m_ex) : 0.f;
    } else {
      // exact f64 rescore, shuffle-only: s = sum_e qd_e*bk_e
      //   + sum_j u_j * x[c][j],  u_j = sum_e qd_e * Wk[h*64+e][j]
      const int he = h * HEAD_E + l;
      const float* wqr = Wq + (size_t)he * D_MODEL;
      const float* xr  = x + (rowbase + q0 + q) * D_MODEL;
      double qd = 0.0;
      for (int j = 0; j < D_MODEL; ++j) qd += (double)wqr[j] * (double)xr[j];
      qd += (double)bq[he];                      // qd = Q[qrow][he] exact f64

      double qkb = qd * (double)bk[he];
#pragma unroll
      for (int off = 1; off < 64; off <<= 1) qkb += __shfl_xor(qkb, off);

      const int crow = (l < C2) ? cidx : 0;
      const float* xc = x + (rowbase + crow) * D_MODEL;
      double s_c = qkb;
      for (int jc = 0; jc < 8; ++jc) {
        const float* wkc = Wk + (jc << 6) + l;
        double uacc = 0.0;
        for (int e = 0; e < 64; ++e) {
          double qde = __shfl(qd, e);
          uacc += qde * (double)wkc[(size_t)(h * HEAD_E + e) * D_MODEL];
        }
        for (int jj = 0; jj < 64; ++jj) {
          double ujj = __shfl(uacc, jj);
          s_c += ujj * (double)xc[(jc << 6) + jj];
        }
      }
      double d = (l < C2) ? s_c * 0.125 : -1.0e300;
      int myi = (l < C2) ? cidx : (2 * SEQ_L + l);
      double mxd = -1.0e300; int rank = 0;
      for (int j = 0; j < 64; ++j) {
        double dj = __shfl(d, j);
        int    ij = __shfl(myi, j);
        if (dj > mxd) mxd = dj;
        rank += (dj > d) || ((dj == d) && (ij < myi));
      }
      myw = (l < C2 && rank < KSEL) ? __expf((float)(d - mxd)) : 0.f;
    }

    float psum = myw;
#pragma unroll
    for (int off = 1; off < 64; off <<= 1) psum += __shfl_xor(psum, off);
    const float inv = 1.0f / psum;

    // ---- PV: branchless, 8 gather loads in flight per batch ----
    const float* Vb = Vf + rowbase * D_MODEL + h * HEAD_E;
    float acc = 0.f;
    const int nn8 = tight ? 64 : 40;   // weights are 0 beyond KSEL/C2
    for (int j0 = 0; j0 < nn8; j0 += 8) {
      float wv8[8]; const float* vp8[8];
#pragma unroll
      for (int u = 0; u < 8; ++u) {
        wv8[u] = __shfl(myw, j0 + u);
        int sj = __shfl(cidx, j0 + u) & (SEQ_L - 1);   // clamp pad lanes
        vp8[u] = Vb + (size_t)sj * D_MODEL + l;
      }
      float vv8[8];
#pragma unroll
      for (int u = 0; u < 8; ++u) vv8[u] = *vp8[u];
#pragma unroll
      for (int u = 0; u < 8; ++u) acc = fmaf(wv8[u], vv8[u], acc);
    }
    AO[(rowbase + q0 + q) * D_MODEL + h * HEAD_E + l] = acc * inv;
  }
}

// ---------------------------------------------------------------------------
extern "C" void kernel_launch(void* const* d_in, const int* in_sizes, int n_in,
                              void* d_out, int out_size, void* d_ws, size_t ws_size,
                              hipStream_t stream) {
  const float* x  = (const float*)d_in[0];
  const float* Wq = (const float*)d_in[1];
  const float* bq = (const float*)d_in[2];
  const float* Wk = (const float*)d_in[3];
  const float* bk = (const float*)d_in[4];
  const float* Wv = (const float*)d_in[5];
  const float* bv = (const float*)d_in[6];
  const float* Wo = (const float*)d_in[7];
  const float* bo = (const float*)d_in[8];
  float* out = (float*)d_out;

  char* ws = (char*)d_ws;
  const size_t MATB = (size_t)M_ROWS * D_MODEL * 4;  // 8 MB
  float* Qf = (float*)ws;
  float* Kf = (float*)(ws + MATB);
  float* Vf = (float*)(ws + 2 * MATB);
  float* AO = (float*)(ws + 3 * MATB);
  unsigned short* Qh = (unsigned short*)(ws + 4 * MATB);            // 4 MB
  unsigned short* Kh = (unsigned short*)(ws + 4 * MATB + MATB / 2); // 4 MB
  float* kemax = (float*)(ws + 5 * MATB);                           // 4 KB

  dim3 qkvgrid(D_MODEL / 64, M_ROWS / 64, 3);
  gemm_qkv_kernel<<<qkvgrid, 256, 0, stream>>>(
      x, Wq, bq, Wk, bk, Wv, bv, Qf, Kf, Vf, Qh, Kh);

  kemax_kernel<<<dim3(BATCH * N_HEADS), 256, 0, stream>>>(Kf, kemax);

  attn_kernel<<<dim3(SEQ_L / 16 * BATCH * N_HEADS), 512, 0, stream>>>(
      Qf, Kf, Vf, Qh, Kh, kemax, x, Wq, bq, Wk, bk, AO);

  dim3 ggrid(D_MODEL / 64, M_ROWS / 64);
  gemm_bias_kernel<<<ggrid, 256, 0, stream>>>(AO, Wo, bo, out, M_ROWS, D_MODEL, D_MODEL);
}

// Round 10
// 801.469 us; speedup vs baseline: 12.6377x; 1.3875x over previous
//
#include <hip/hip_runtime.h>
#include <hip/hip_fp16.h>
#include <cstdint>
#include <cstddef>

#define D_MODEL 512
#define N_HEADS 8
#define HEAD_E  64
#define SEQ_L   2048
#define BATCH   2
#define KSEL    38            // int(5*log(2048)) = 38
#define M_ROWS  (BATCH*SEQ_L) // 4096
#define SP      2050          // S row stride (f16): odd dword stride de-banks rows
#define CCAP    192           // candidate cap (3 per lane); overflow -> exact rescan

typedef short bf16x8 __attribute__((ext_vector_type(8)));
typedef float f32x4  __attribute__((ext_vector_type(4)));

static __device__ __forceinline__ unsigned short f2bf(float x) {
  uint32_t u = __float_as_uint(x);
  return (unsigned short)((u + 0x7FFF + ((u >> 16) & 1)) >> 16);  // RNE
}

// ---------------------------------------------------------------------------
// Fused QKV f32 GEMM: z=0:Q, z=1:K, z=2:V. C = x @ W.T + b.
// Q,K also emit bf16 copies for the MFMA score scan.
// ---------------------------------------------------------------------------
__global__ __launch_bounds__(256) void gemm_qkv_kernel(
    const float* __restrict__ A,
    const float* __restrict__ Wq, const float* __restrict__ bq,
    const float* __restrict__ Wk, const float* __restrict__ bk,
    const float* __restrict__ Wv, const float* __restrict__ bv,
    float* __restrict__ Qf, float* __restrict__ Kf, float* __restrict__ Vf,
    unsigned short* __restrict__ Qh, unsigned short* __restrict__ Kh)
{
  const int z = blockIdx.z;
  const float* W    = (z == 0) ? Wq : ((z == 1) ? Wk : Wv);
  const float* bias = (z == 0) ? bq : ((z == 1) ? bk : bv);
  float* C          = (z == 0) ? Qf : ((z == 1) ? Kf : Vf);
  unsigned short* Ch = (z == 0) ? Qh : ((z == 1) ? Kh : nullptr);

  __shared__ float As[64][36];
  __shared__ float Ws[64][36];
  const int t  = threadIdx.x;
  const int tx = t & 15, ty = t >> 4;
  const int bm = blockIdx.y << 6, bn = blockIdx.x << 6;

  float acc[4][4] = {};

  for (int k0 = 0; k0 < D_MODEL; k0 += 32) {
    __syncthreads();
#pragma unroll
    for (int i = 0; i < 2; ++i) {
      int f = t + (i << 8);
      int r = f >> 3, c = (f & 7) << 2;
      *(float4*)&As[r][c] = *(const float4*)&A[(size_t)(bm + r) * D_MODEL + k0 + c];
      *(float4*)&Ws[r][c] = *(const float4*)&W[(size_t)(bn + r) * D_MODEL + k0 + c];
    }
    __syncthreads();
#pragma unroll
    for (int kk = 0; kk < 32; kk += 4) {
      float4 av[4], wv[4];
#pragma unroll
      for (int i = 0; i < 4; ++i) av[i] = *(const float4*)&As[ty * 4 + i][kk];
#pragma unroll
      for (int j = 0; j < 4; ++j) wv[j] = *(const float4*)&Ws[tx + 16 * j][kk];
#pragma unroll
      for (int i = 0; i < 4; ++i)
#pragma unroll
        for (int j = 0; j < 4; ++j)
          acc[i][j] += av[i].x * wv[j].x + av[i].y * wv[j].y +
                       av[i].z * wv[j].z + av[i].w * wv[j].w;
    }
  }

#pragma unroll
  for (int i = 0; i < 4; ++i) {
    int row = bm + ty * 4 + i;
#pragma unroll
    for (int j = 0; j < 4; ++j) {
      int col = bn + tx + 16 * j;
      float v = acc[i][j] + bias[col];
      size_t idx = (size_t)row * D_MODEL + col;
      C[idx] = v;
      if (Ch) Ch[idx] = f2bf(v);
    }
  }
}

// ---------------------------------------------------------------------------
// f32 GEMM (output projection): C = A @ W.T + b
// ---------------------------------------------------------------------------
__global__ __launch_bounds__(256) void gemm_bias_kernel(
    const float* __restrict__ A, const float* __restrict__ W,
    const float* __restrict__ bias, float* __restrict__ C,
    int M, int N, int K)
{
  __shared__ float As[64][36];
  __shared__ float Ws[64][36];
  const int t  = threadIdx.x;
  const int tx = t & 15, ty = t >> 4;
  const int bm = blockIdx.y << 6, bn = blockIdx.x << 6;

  float acc[4][4] = {};

  for (int k0 = 0; k0 < K; k0 += 32) {
    __syncthreads();
#pragma unroll
    for (int i = 0; i < 2; ++i) {
      int f = t + (i << 8);
      int r = f >> 3, c = (f & 7) << 2;
      *(float4*)&As[r][c] = *(const float4*)&A[(size_t)(bm + r) * K + k0 + c];
      *(float4*)&Ws[r][c] = *(const float4*)&W[(size_t)(bn + r) * K + k0 + c];
    }
    __syncthreads();
#pragma unroll
    for (int kk = 0; kk < 32; kk += 4) {
      float4 av[4], wv[4];
#pragma unroll
      for (int i = 0; i < 4; ++i) av[i] = *(const float4*)&As[ty * 4 + i][kk];
#pragma unroll
      for (int j = 0; j < 4; ++j) wv[j] = *(const float4*)&Ws[tx + 16 * j][kk];
#pragma unroll
      for (int i = 0; i < 4; ++i)
#pragma unroll
        for (int j = 0; j < 4; ++j)
          acc[i][j] += av[i].x * wv[j].x + av[i].y * wv[j].y +
                       av[i].z * wv[j].z + av[i].w * wv[j].w;
    }
  }

#pragma unroll
  for (int i = 0; i < 4; ++i) {
    int row = bm + ty * 4 + i;
#pragma unroll
    for (int j = 0; j < 4; ++j) {
      int col = bn + tx + 16 * j;
      C[(size_t)row * N + col] = acc[i][j] + bias[col];
    }
  }
}

// ---------------------------------------------------------------------------
// Per-(b,h,e) max |K_e| over keys — feeds the rigorous bf16-error margin.
// ---------------------------------------------------------------------------
__global__ __launch_bounds__(256) void kemax_kernel(
    const float* __restrict__ Kf, float* __restrict__ kemax)
{
  const int bh = blockIdx.x;
  const int b = bh >> 3, h = bh & 7;
  const int e = threadIdx.x & 63, chunk = threadIdx.x >> 6;
  const float* base = Kf + ((size_t)b * SEQ_L) * D_MODEL + h * HEAD_E + e;
  float mx = 0.f;
  for (int k = chunk * 512; k < chunk * 512 + 512; ++k)
    mx = fmaxf(mx, fabsf(base[(size_t)k * D_MODEL]));
  __shared__ float red[4][64];
  red[chunk][e] = mx;
  __syncthreads();
  if (threadIdx.x < 64) {
    float m0 = fmaxf(fmaxf(red[0][threadIdx.x], red[1][threadIdx.x]),
                     fmaxf(red[2][threadIdx.x], red[3][threadIdx.x]));
    kemax[bh * 64 + threadIdx.x] = m0;
  }
}

// ---------------------------------------------------------------------------
// Fused ProbSparse attention v10 — v9 structure; single lever this round:
//  * tight threshold 3e-4 -> 2e-5 (12x margin over the 1.6e-6 max f32-chain
//    error; cuts f64-fallback invocations ~13% -> ~1% of queries).
//  * surviving f64 fallback made ~4x cheaper: float4 row loads (4x fewer
//    cache-line touches in the per-lane-row gather) + 4-way split
//    accumulators (break serial f64 FMA chains).
// Everything else byte-identical to v9.
// ---------------------------------------------------------------------------
__global__ __launch_bounds__(512) void attn_kernel(
    const float* __restrict__ Qf, const float* __restrict__ Kf,
    const float* __restrict__ Vf,
    const unsigned short* __restrict__ Qh, const unsigned short* __restrict__ Kh,
    const float* __restrict__ kemax,
    const float* __restrict__ x,
    const float* __restrict__ Wq, const float* __restrict__ bq,
    const float* __restrict__ Wk, const float* __restrict__ bk,
    float* __restrict__ AO)
{
  __shared__ __half  S[16][SP];          // 65600 B approx scores
  __shared__ short   cis2[8][CCAP];      // captured candidate indices
  __shared__ float   cvs[8][64];         // exact candidates (post bisect)
  __shared__ short   cis[8][64];
  __shared__ float   qrowL[8][64];       // per-wave f32 q row
  __shared__ float   kemaxL[64];

  const int t    = threadIdx.x;
  const int w    = t >> 6;
  const int l    = t & 63;

  // XCD-affine decode: round-robin dispatch puts wg&7 on XCD (wg&7).
  const int wg   = blockIdx.x;
  const int xcd  = wg & 7;
  const int idx  = wg >> 3;              // 0..255
  const int bh   = xcd + 8 * (idx >> 7); // XCD handles bh, then bh+8
  const int qblk = idx & 127;
  const int b    = bh >> 3, h = bh & 7;
  const int q0   = qblk << 4;
  const size_t rowbase = (size_t)b * SEQ_L;

  if (t < 64) kemaxL[t] = kemax[bh * 64 + t];

  // ---- MFMA score scan: wave w covers keys [w*256, w*256+256) ----
  {
    const int lo16 = l & 15, grp = l >> 4;
    const unsigned short* qrow =
        Qh + (rowbase + q0 + lo16) * D_MODEL + h * HEAD_E;
    bf16x8 a0 = *(const bf16x8*)&qrow[grp * 8];
    bf16x8 a1 = *(const bf16x8*)&qrow[32 + grp * 8];

    const int kbase = w * 256;
#pragma unroll
    for (int kt = 0; kt < 4; ++kt) {
#pragma unroll
      for (int kc = 0; kc < 4; ++kc) {
        const int key0 = kbase + kt * 64 + kc * 16 + lo16;
        const unsigned short* krow =
            Kh + (rowbase + key0) * D_MODEL + h * HEAD_E;
        bf16x8 b0 = *(const bf16x8*)&krow[grp * 8];
        bf16x8 b1 = *(const bf16x8*)&krow[32 + grp * 8];
        f32x4 acc = {0.f, 0.f, 0.f, 0.f};
        acc = __builtin_amdgcn_mfma_f32_16x16x32_bf16(a0, b0, acc, 0, 0, 0);
        acc = __builtin_amdgcn_mfma_f32_16x16x32_bf16(a1, b1, acc, 0, 0, 0);
#pragma unroll
        for (int r = 0; r < 4; ++r)
          S[grp * 4 + r][key0] = __float2half(acc[r] * 0.125f);
      }
    }
  }
  __syncthreads();

  // ---- selection: wave w handles queries 2w, 2w+1 ----
  for (int qq = 0; qq < 2; ++qq) {
    const int q = 2 * w + qq;

    qrowL[w][l] = Qf[(rowbase + q0 + q) * D_MODEL + h * HEAD_E + l];

    float v[32];
#pragma unroll
    for (int j = 0; j < 32; ++j) v[j] = __half2float(S[q][(j << 6) + l]);

    float m = v[0];
#pragma unroll
    for (int j = 1; j < 32; ++j) m = fmaxf(m, v[j]);
#pragma unroll
    for (int off = 1; off < 64; off <<= 1) m = fmaxf(m, __shfl_xor(m, off));

    auto countge = [&](float T) -> int {
      int c = 0;
#pragma unroll
      for (int j = 0; j < 32; ++j) c += (v[j] >= T) ? 1 : 0;
#pragma unroll
      for (int off = 1; off < 64; off <<= 1) c += __shfl_xor(c, off);
      return c;
    };

    // approx bisect: count(>=lo) in [40, 64] (>=40 guaranteed)
    float lo = m - 0.5f;
    int C = countge(lo);
    float step = 1.0f;
    while (C < 40) {
      lo -= step; step *= 2.0f;
      if (step > 1.0e30f) { lo = -3.0e38f; C = 2048; break; }
      C = countge(lo);
    }
    float hi = m;
    for (int it = 0; it < 24 && C > 64; ++it) {
      float mid = 0.5f * (lo + hi);
      int cm = countge(mid);
      if (cm >= 40) { lo = mid; C = cm; } else hi = mid;
    }

    // provable margin (bf16 RNE + f16 store + mfma accum), 2x slack
    float red = fabsf(qrowL[w][l]) * kemaxL[l];
#pragma unroll
    for (int off = 1; off < 64; off <<= 1) red += __shfl_xor(red, off);
    const float lo2 = lo - (red * 0.0025f + 0.008f);

    // capture candidate indices (approx >= lo2) in key order
    int base = 0;
#pragma unroll
    for (int j = 0; j < 32; ++j) {
      bool in = (v[j] >= lo2);
      unsigned long long mk = __ballot(in);
      if (in) {
        int pos = base + (int)__popcll(mk & ((1ull << l) - 1ull));
        if (pos < CCAP) cis2[w][pos] = (short)((j << 6) | l);
      }
      base += (int)__popcll(mk);
    }

    int C2;
    if (base <= CCAP) {
      // ---- common path: exact f32 rescore of captured candidates ----
      const int count2 = base;
      const int i0 = l, i1 = 64 + l, i2 = 128 + l;
      const int idx0 = (i0 < count2) ? (int)cis2[w][i0] : 0;
      const int idx1 = (i1 < count2) ? (int)cis2[w][i1] : 0;
      const int idx2 = (i2 < count2) ? (int)cis2[w][i2] : 0;
      float e0 = -3.0e38f, e1 = -3.0e38f, e2 = -3.0e38f;
      {
        const float* kr0 = Kf + (rowbase + idx0) * D_MODEL + h * HEAD_E;
        const float* kr1 = Kf + (rowbase + idx1) * D_MODEL + h * HEAD_E;
        const float* kr2 = Kf + (rowbase + idx2) * D_MODEL + h * HEAD_E;
        float r0 = 0.f, r1 = 0.f, r2 = 0.f;
#pragma unroll
        for (int e4 = 0; e4 < 16; ++e4) {
          float4 qv = *(const float4*)&qrowL[w][e4 * 4];
          float4 k0 = *(const float4*)&kr0[e4 * 4];
          float4 k1 = *(const float4*)&kr1[e4 * 4];
          float4 k2 = *(const float4*)&kr2[e4 * 4];
          r0 += qv.x * k0.x + qv.y * k0.y + qv.z * k0.z + qv.w * k0.w;
          r1 += qv.x * k1.x + qv.y * k1.y + qv.z * k1.z + qv.w * k1.w;
          r2 += qv.x * k2.x + qv.y * k2.y + qv.z * k2.z + qv.w * k2.w;
        }
        if (i0 < count2) e0 = r0 * 0.125f;
        if (i1 < count2) e1 = r1 * 0.125f;
        if (i2 < count2) e2 = r2 * 0.125f;
      }

      // exact bisect to count in [40, 64]
      float hiv = fmaxf(fmaxf(e0, e1), e2);
      float lov = fminf(fminf((i0 < count2) ? e0 : 3.0e38f,
                              (i1 < count2) ? e1 : 3.0e38f),
                              (i2 < count2) ? e2 : 3.0e38f);
#pragma unroll
      for (int off = 1; off < 64; off <<= 1) {
        hiv = fmaxf(hiv, __shfl_xor(hiv, off));
        lov = fminf(lov, __shfl_xor(lov, off));
      }
      lov -= 1e-3f;
      for (int it = 0; it < 30; ++it) {
        int c = (int)__popcll(__ballot(e0 >= lov)) +
                (int)__popcll(__ballot(e1 >= lov)) +
                (int)__popcll(__ballot(e2 >= lov));
        if (c <= 64) break;
        float mid = 0.5f * (lov + hiv);
        int cm = (int)__popcll(__ballot(e0 >= mid)) +
                 (int)__popcll(__ballot(e1 >= mid)) +
                 (int)__popcll(__ballot(e2 >= mid));
        if (cm >= 40) lov = mid; else hiv = mid;
      }

      // compact exact-selected into cvs/cis (key order preserved)
      bool in0 = (e0 >= lov);
      bool in1 = (e1 >= lov);
      bool in2 = (e2 >= lov);
      unsigned long long m0 = __ballot(in0);
      unsigned long long m1 = __ballot(in1);
      unsigned long long m2 = __ballot(in2);
      int tot0 = (int)__popcll(m0), tot1 = (int)__popcll(m1);
      if (in0) {
        int p = (int)__popcll(m0 & ((1ull << l) - 1ull));
        if (p < 64) { cvs[w][p] = e0; cis[w][p] = (short)idx0; }
      }
      if (in1) {
        int p = tot0 + (int)__popcll(m1 & ((1ull << l) - 1ull));
        if (p < 64) { cvs[w][p] = e1; cis[w][p] = (short)idx1; }
      }
      if (in2) {
        int p = tot0 + tot1 + (int)__popcll(m2 & ((1ull << l) - 1ull));
        if (p < 64) { cvs[w][p] = e2; cis[w][p] = (short)idx2; }
      }
      int tot = tot0 + tot1 + (int)__popcll(m2);
      C2 = (tot < 64) ? tot : 64;
    } else {
      // ---- rare overflow path: exact f32 rescan of ALL keys (no cap) ----
#pragma unroll 4
      for (int j = 0; j < 32; ++j) {
        const float* kr = Kf + (rowbase + (j << 6) + l) * D_MODEL + h * HEAD_E;
        float r0 = 0.f, r1 = 0.f;
#pragma unroll
        for (int e4 = 0; e4 < 16; e4 += 2) {
          float4 qv0 = *(const float4*)&qrowL[w][e4 * 4];
          float4 qv1 = *(const float4*)&qrowL[w][e4 * 4 + 4];
          float4 k0 = *(const float4*)&kr[e4 * 4];
          float4 k1 = *(const float4*)&kr[e4 * 4 + 4];
          r0 += qv0.x * k0.x + qv0.y * k0.y + qv0.z * k0.z + qv0.w * k0.w;
          r1 += qv1.x * k1.x + qv1.y * k1.y + qv1.z * k1.z + qv1.w * k1.w;
        }
        v[j] = (r0 + r1) * 0.125f;   // v now holds EXACT f32 scores
      }
      float hiv = v[0], lov = v[0];
#pragma unroll
      for (int j = 1; j < 32; ++j) {
        hiv = fmaxf(hiv, v[j]); lov = fminf(lov, v[j]);
      }
#pragma unroll
      for (int off = 1; off < 64; off <<= 1) {
        hiv = fmaxf(hiv, __shfl_xor(hiv, off));
        lov = fminf(lov, __shfl_xor(lov, off));
      }
      lov -= 1e-3f;
      for (int it = 0; it < 30; ++it) {
        int c = countge(lov);
        if (c <= 64) break;
        float mid = 0.5f * (lov + hiv);
        int cm = countge(mid);
        if (cm >= 40) lov = mid; else hiv = mid;
      }
      int bb = 0;
#pragma unroll
      for (int j = 0; j < 32; ++j) {
        bool in = (v[j] >= lov);
        unsigned long long mk = __ballot(in);
        if (in) {
          int pos = bb + (int)__popcll(mk & ((1ull << l) - 1ull));
          if (pos < 64) { cvs[w][pos] = v[j]; cis[w][pos] = (short)((j << 6) + l); }
        }
        bb += (int)__popcll(mk);
      }
      C2 = (bb < 64) ? bb : 64;
    }

    float cval = (l < C2) ? cvs[w][l] : -3.0e38f;
    int   cidx = (l < C2) ? (int)cis[w][l] : (2 * SEQ_L + l);

    // bitonic sort 64: value desc, index asc
#pragma unroll
    for (int sz = 2; sz <= 64; sz <<= 1) {
#pragma unroll
      for (int st = sz >> 1; st >= 1; st >>= 1) {
        float ov = __shfl_xor(cval, st);
        int   oi = __shfl_xor(cidx, st);
        bool ob    = (ov > cval) || ((ov == cval) && (oi < cidx));
        bool dir   = ((l & sz) == 0);
        bool lower = ((l & st) == 0);
        if (ob == (lower == dir)) { cval = ov; cidx = oi; }
      }
    }

    const float m_ex = __shfl(cval, 0);
    const float v37  = __shfl(cval, 37);
    const float v38  = __shfl(cval, 38);
    const bool tight = (v37 - v38 < 2e-5f);   // 12x margin over max f32-chain err

    float myw;
    if (!tight) {
      myw = (l < KSEL) ? __expf(cval - m_ex) : 0.f;
    } else {
      // exact f64 rescore, shuffle-only: s = sum_e qd_e*bk_e
      //   + sum_j u_j * x[c][j],  u_j = sum_e qd_e * Wk[h*64+e][j]
      const int he = h * HEAD_E + l;
      const float* wqr = Wq + (size_t)he * D_MODEL;
      const float* xr  = x + (rowbase + q0 + q) * D_MODEL;
      double qa0 = 0.0, qa1 = 0.0, qa2 = 0.0, qa3 = 0.0;
      for (int j = 0; j < D_MODEL; j += 4) {     // float4: 4x fewer line touches
        float4 wq4 = *(const float4*)&wqr[j];
        float4 x4  = *(const float4*)&xr[j];
        qa0 += (double)wq4.x * (double)x4.x;
        qa1 += (double)wq4.y * (double)x4.y;
        qa2 += (double)wq4.z * (double)x4.z;
        qa3 += (double)wq4.w * (double)x4.w;
      }
      double qd = ((qa0 + qa1) + (qa2 + qa3)) + (double)bq[he];

      double qkb = qd * (double)bk[he];
#pragma unroll
      for (int off = 1; off < 64; off <<= 1) qkb += __shfl_xor(qkb, off);

      const int crow = (l < C2) ? cidx : 0;
      const float* xc = x + (rowbase + crow) * D_MODEL;
      double s_c = qkb;
      for (int jc = 0; jc < 8; ++jc) {
        const float* wkc = Wk + (jc << 6) + l;
        double u0 = 0.0, u1 = 0.0;
        for (int e = 0; e < 64; e += 2) {       // 2 chains: halve dep latency
          double qde0 = __shfl(qd, e);
          double qde1 = __shfl(qd, e + 1);
          u0 += qde0 * (double)wkc[(size_t)(h * HEAD_E + e) * D_MODEL];
          u1 += qde1 * (double)wkc[(size_t)(h * HEAD_E + e + 1) * D_MODEL];
        }
        double uacc = u0 + u1;
        double s0 = 0.0, s1 = 0.0;
        for (int jj = 0; jj < 64; jj += 2) {
          double uj0 = __shfl(uacc, jj);
          double uj1 = __shfl(uacc, jj + 1);
          s0 += uj0 * (double)xc[(jc << 6) + jj];
          s1 += uj1 * (double)xc[(jc << 6) + jj + 1];
        }
        s_c += s0 + s1;
      }
      double d = (l < C2) ? s_c * 0.125 : -1.0e300;
      int myi = (l < C2) ? cidx : (2 * SEQ_L + l);
      double mxd = -1.0e300; int rank = 0;
      for (int j = 0; j < 64; ++j) {
        double dj = __shfl(d, j);
        int    ij = __shfl(myi, j);
        if (dj > mxd) mxd = dj;
        rank += (dj > d) || ((dj == d) && (ij < myi));
      }
      myw = (l < C2 && rank < KSEL) ? __expf((float)(d - mxd)) : 0.f;
    }

    float psum = myw;
#pragma unroll
    for (int off = 1; off < 64; off <<= 1) psum += __shfl_xor(psum, off);
    const float inv = 1.0f / psum;

    // ---- PV: branchless, 8 gather loads in flight per batch ----
    const float* Vb = Vf + rowbase * D_MODEL + h * HEAD_E;
    float acc = 0.f;
    const int nn8 = tight ? 64 : 40;   // weights are 0 beyond KSEL/C2
    for (int j0 = 0; j0 < nn8; j0 += 8) {
      float wv8[8]; const float* vp8[8];
#pragma unroll
      for (int u = 0; u < 8; ++u) {
        wv8[u] = __shfl(myw, j0 + u);
        int sj = __shfl(cidx, j0 + u) & (SEQ_L - 1);   // clamp pad lanes
        vp8[u] = Vb + (size_t)sj * D_MODEL + l;
      }
      float vv8[8];
#pragma unroll
      for (int u = 0; u < 8; ++u) vv8[u] = *vp8[u];
#pragma unroll
      for (int u = 0; u < 8; ++u) acc = fmaf(wv8[u], vv8[u], acc);
    }
    AO[(rowbase + q0 + q) * D_MODEL + h * HEAD_E + l] = acc * inv;
  }
}

// ---------------------------------------------------------------------------
extern "C" void kernel_launch(void* const* d_in, const int* in_sizes, int n_in,
                              void* d_out, int out_size, void* d_ws, size_t ws_size,
                              hipStream_t stream) {
  const float* x  = (const float*)d_in[0];
  const float* Wq = (const float*)d_in[1];
  const float* bq = (const float*)d_in[2];
  const float* Wk = (const float*)d_in[3];
  const float* bk = (const float*)d_in[4];
  const float* Wv = (const float*)d_in[5];
  const float* bv = (const float*)d_in[6];
  const float* Wo = (const float*)d_in[7];
  const float* bo = (const float*)d_in[8];
  float* out = (float*)d_out;

  char* ws = (char*)d_ws;
  const size_t MATB = (size_t)M_ROWS * D_MODEL * 4;  // 8 MB
  float* Qf = (float*)ws;
  float* Kf = (float*)(ws + MATB);
  float* Vf = (float*)(ws + 2 * MATB);
  float* AO = (float*)(ws + 3 * MATB);
  unsigned short* Qh = (unsigned short*)(ws + 4 * MATB);            // 4 MB
  unsigned short* Kh = (unsigned short*)(ws + 4 * MATB + MATB / 2); // 4 MB
  float* kemax = (float*)(ws + 5 * MATB);                           // 4 KB

  dim3 qkvgrid(D_MODEL / 64, M_ROWS / 64, 3);
  gemm_qkv_kernel<<<qkvgrid, 256, 0, stream>>>(
      x, Wq, bq, Wk, bk, Wv, bv, Qf, Kf, Vf, Qh, Kh);

  kemax_kernel<<<dim3(BATCH * N_HEADS), 256, 0, stream>>>(Kf, kemax);

  attn_kernel<<<dim3(SEQ_L / 16 * BATCH * N_HEADS), 512, 0, stream>>>(
      Qf, Kf, Vf, Qh, Kh, kemax, x, Wq, bq, Wk, bk, AO);

  dim3 ggrid(D_MODEL / 64, M_ROWS / 64);
  gemm_bias_kernel<<<ggrid, 256, 0, stream>>>(AO, Wo, bo, out, M_ROWS, D_MODEL, D_MODEL);
}